// Round 1
// baseline (496.567 us; speedup 1.0000x reference)
//
#include <hip/hip_runtime.h>
#include <cstdint>

// ---------------------------------------------------------------------------
// VAE attention block: GN -> QKV 1x1 conv -> softmax(QK^T) V -> proj + x
// B=4, H=W=64 (N=4096 pixels/batch), C=512, GROUPS=32
// R7: scores + PV fused into a flash-attention kernel (fp8 MX MFMA):
//   - eliminates the 67 MB sc8 intermediate (write+read) and lrow atomics
//   - 1 block = 64 Q-rows x full KV sweep; 256 blocks, 8 waves
//   - Q fragments held in registers (S wave-tile 16x64); K/V fragments
//     loaded global->reg (single-use); P via 8 KB XOR-swizzled fp8 LDS tile
//   - row-sums l accumulated in registers across tiles, reduced once at end
// ---------------------------------------------------------------------------

typedef __bf16 bf16_t;
typedef bf16_t bf16x8 __attribute__((ext_vector_type(8)));
typedef float floatx4 __attribute__((ext_vector_type(4)));
typedef int v8i __attribute__((ext_vector_type(8)));

__device__ __forceinline__ uint16_t f2b(float f) {
    uint32_t u = __builtin_bit_cast(uint32_t, f);
    u += 0x7fffu + ((u >> 16) & 1u);
    return (uint16_t)(u >> 16);
}
__device__ __forceinline__ float b2f(uint16_t h) {
    uint32_t u = ((uint32_t)h) << 16;
    return __builtin_bit_cast(float, u);
}
// pack 4 floats -> 4 fp8 e4m3 bytes (byte 0 = first arg)
__device__ __forceinline__ unsigned pk_fp8x4(float a, float b, float c, float d) {
    int w = __builtin_amdgcn_cvt_pk_fp8_f32(a, b, 0, false);
    w = __builtin_amdgcn_cvt_pk_fp8_f32(c, d, w, true);
    return (unsigned)w;
}

__device__ __forceinline__ void lds_copy16(void* lds, const void* glob) {
    __builtin_amdgcn_global_load_lds(
        (__attribute__((address_space(1))) void*)(void*)glob,
        (__attribute__((address_space(3))) void*)lds,
        16, 0, 0);
}

// ---------------------------------------------------------------------------
// GroupNorm stats: one block per (batch, group).
// ---------------------------------------------------------------------------
__global__ __launch_bounds__(256) void gn_stats(const float* __restrict__ x,
                                                float* __restrict__ stats) {
    const int bg = blockIdx.x;            // 0..127
    const int tid = threadIdx.x;
    const int b = bg >> 5, g = bg & 31;
    const float* base = x + (long)b * (4096L * 512) + g * 16;
    float s = 0.f, sq = 0.f;
    #pragma unroll 8
    for (int i = 0; i < 64; i++) {
        int idx4 = tid + i * 256;          // float4 index within group
        int pixel = idx4 >> 2, c4 = idx4 & 3;
        const float4 v = *(const float4*)(base + (long)pixel * 512 + c4 * 4);
        s += v.x + v.y + v.z + v.w;
        sq += v.x * v.x + v.y * v.y + v.z * v.z + v.w * v.w;
    }
    #pragma unroll
    for (int off = 32; off > 0; off >>= 1) {
        s += __shfl_down(s, off);
        sq += __shfl_down(sq, off);
    }
    __shared__ float rs[4], rq[4];
    const int lane = tid & 63, w = tid >> 6;
    if (lane == 0) { rs[w] = s; rq[w] = sq; }
    __syncthreads();
    if (tid == 0) {
        float S = rs[0] + rs[1] + rs[2] + rs[3];
        float Q = rq[0] + rq[1] + rq[2] + rq[3];
        float mean = S * (1.f / 65536.f);
        float var = Q * (1.f / 65536.f) - mean * mean;
        stats[bg * 2 + 0] = mean;
        stats[bg * 2 + 1] = rsqrtf(var + 1e-5f);
    }
}

// ---------------------------------------------------------------------------
// GroupNorm apply: h_bf16 = (x-mean)*rstd*gamma + beta.  4 elems/thread.
// ---------------------------------------------------------------------------
__global__ __launch_bounds__(256) void gn_apply(const float* __restrict__ x,
                                                const float* __restrict__ stats,
                                                const float* __restrict__ gamma,
                                                const float* __restrict__ beta,
                                                uint16_t* __restrict__ h) {
    const long idx4 = (long)blockIdx.x * 256 + threadIdx.x;   // 0..2097151
    const long e0 = idx4 * 4;
    const int c = (int)(e0 & 511);
    const int b = (int)(e0 >> 21);                            // 4096*512 = 2^21
    const float2 st = ((const float2*)stats)[b * 32 + (c >> 4)];
    const float4 v = ((const float4*)x)[idx4];
    const float4 gm = ((const float4*)gamma)[c >> 2];
    const float4 bt = ((const float4*)beta)[c >> 2];
    union { ushort4 u; uint16_t s[4]; } o;
    o.s[0] = f2b((v.x - st.x) * st.y * gm.x + bt.x);
    o.s[1] = f2b((v.y - st.x) * st.y * gm.y + bt.y);
    o.s[2] = f2b((v.z - st.x) * st.y * gm.z + bt.z);
    o.s[3] = f2b((v.w - st.x) * st.y * gm.w + bt.w);
    ((ushort4*)h)[idx4] = o.u;
}

// ---------------------------------------------------------------------------
// Cast+transpose weights: wT[d][c] = bf16(w[c][d]), 512x512, 64x64 LDS tiles.
// ---------------------------------------------------------------------------
__global__ __launch_bounds__(256) void wcast_transpose(const float* __restrict__ w0,
                                                       const float* __restrict__ w1,
                                                       const float* __restrict__ w2,
                                                       const float* __restrict__ w3,
                                                       uint16_t* __restrict__ out) {
    const float* ws[4] = {w0, w1, w2, w3};
    const float* w = ws[blockIdx.z];
    uint16_t* o = out + (long)blockIdx.z * 512 * 512;
    __shared__ uint16_t t[64][65];
    const int nb = blockIdx.x * 64, kb = blockIdx.y * 64;
    const int lc = threadIdx.x & 63, lg = threadIdx.x >> 6;
    #pragma unroll
    for (int i = 0; i < 16; i++) {
        int r = lg * 16 + i;
        t[lc][r] = f2b(w[(long)(kb + r) * 512 + nb + lc]);   // t[n_loc][k_loc]
    }
    __syncthreads();
    #pragma unroll
    for (int i = 0; i < 16; i++) {
        int r = lg * 16 + i;
        o[(long)(nb + r) * 512 + kb + lc] = t[r][lc];        // wT[n][k]
    }
}

// ---------------------------------------------------------------------------
// Fused QKV GEMM (bf16 MFMA): [16384,512] x [1536,512]^T.  Grid (12, 128).
// Outputs fp8 e4m3: cols 0-511 -> q, 512-1023 -> k, 1024-1535 -> v stored
// TRANSPOSED (vt[b][ch][pix]).  No scale on q (moved to flash epilogue).
// ---------------------------------------------------------------------------
__global__ __launch_bounds__(256) void qkv_gemm(const uint16_t* __restrict__ h,
                                                const uint16_t* __restrict__ wT,
                                                const float* __restrict__ bq,
                                                const float* __restrict__ bk,
                                                const float* __restrict__ bv,
                                                uint8_t* __restrict__ q,
                                                uint8_t* __restrict__ k,
                                                uint8_t* __restrict__ vt) {
    __shared__ __align__(16) uint16_t smem[128 * 136];
    uint16_t* sA = smem;
    uint16_t* sB = smem + 8192;

    const int tid = threadIdx.x;
    const long m0 = (long)blockIdx.y * 128;
    const int n0 = blockIdx.x * 128;

    const int lane = tid & 63;
    const int wave = tid >> 6;
    const int wm = (wave & 1) * 64;
    const int wn = (wave >> 1) * 64;
    const int fr = lane & 15;
    const int fh = lane >> 4;
    const int sw = fr & 7;

    floatx4 acc[4][4];
    #pragma unroll
    for (int i = 0; i < 4; i++)
        #pragma unroll
        for (int j = 0; j < 4; j++) acc[i][j] = (floatx4){0.f, 0.f, 0.f, 0.f};

    for (int kt = 0; kt < 512; kt += 64) {
        __syncthreads();
        #pragma unroll
        for (int i = 0; i < 4; i++) {
            const int c = i * 256 + tid;
            const int row = c >> 3;
            const int gj = (c & 7) ^ (row & 7);
            lds_copy16(&sA[c * 8], h + (m0 + row) * 512L + kt + gj * 8);
            lds_copy16(&sB[c * 8], wT + (n0 + row) * 512L + kt + gj * 8);
        }
        __syncthreads();
        #pragma unroll
        for (int kk = 0; kk < 64; kk += 32) {
            const int jx = ((fh + (kk >> 3)) ^ sw) * 8;
            bf16x8 av[4], bv_[4];
            #pragma unroll
            for (int mi = 0; mi < 4; mi++)
                av[mi] = *(const bf16x8*)&sA[(wm + mi * 16 + fr) * 64 + jx];
            #pragma unroll
            for (int ni = 0; ni < 4; ni++)
                bv_[ni] = *(const bf16x8*)&sB[(wn + ni * 16 + fr) * 64 + jx];
            #pragma unroll
            for (int mi = 0; mi < 4; mi++)
                #pragma unroll
                for (int ni = 0; ni < 4; ni++)
                    acc[mi][ni] = __builtin_amdgcn_mfma_f32_16x16x32_bf16(
                        av[mi], bv_[ni], acc[mi][ni], 0, 0, 0);
        }
    }

    const int quad = lane >> 4;
    const int w = n0 >> 9;          // 0=q, 1=k, 2=v(T)
    const int nc = n0 & 511;
    const float* bias = (w == 0) ? bq : (w == 1) ? bk : bv;
    __syncthreads();
    if (w < 2) {
        // repack bf16 rows, then fp8-convert during the coalesced store
        #pragma unroll
        for (int ni = 0; ni < 4; ni++) {
            const int col_l = wn + ni * 16 + fr;
            const float bb = bias[nc + col_l];
            #pragma unroll
            for (int mi = 0; mi < 4; mi++) {
                #pragma unroll
                for (int r = 0; r < 4; r++) {
                    const int row_l = wm + mi * 16 + quad * 4 + r;
                    smem[row_l * 136 + col_l] = f2b(acc[mi][ni][r] + bb);
                }
            }
        }
        __syncthreads();
        uint8_t* out = (w == 0) ? q : k;
        #pragma unroll
        for (int it = 0; it < 8; it++) {
            const int row_l = it * 16 + (tid >> 4);
            const int c0 = (tid & 15) * 8;
            const uint4 d = *(const uint4*)&smem[row_l * 136 + c0];
            const uint16_t* e = (const uint16_t*)&d;
            uint2 o;
            o.x = pk_fp8x4(b2f(e[0]), b2f(e[1]), b2f(e[2]), b2f(e[3]));
            o.y = pk_fp8x4(b2f(e[4]), b2f(e[5]), b2f(e[6]), b2f(e[7]));
            *(uint2*)&out[(m0 + row_l) * 512 + nc + c0] = o;
        }
    } else {
        // transposed fp8 repack: s8[ch][pix], byte stride 144 (16B-aligned)
        uint8_t* s8 = (uint8_t*)smem;
        #pragma unroll
        for (int ni = 0; ni < 4; ni++) {
            const int ch_l = wn + ni * 16 + fr;
            const float bb = bias[nc + ch_l];
            #pragma unroll
            for (int mi = 0; mi < 4; mi++) {
                const int pix0 = wm + mi * 16 + quad * 4;
                *(unsigned*)&s8[ch_l * 144 + pix0] =
                    pk_fp8x4(acc[mi][ni][0] + bb, acc[mi][ni][1] + bb,
                             acc[mi][ni][2] + bb, acc[mi][ni][3] + bb);
            }
        }
        __syncthreads();
        const long b = m0 >> 12;
        const int pixb = (int)(m0 & 4095);
        uint8_t* vtb = vt + b * (512L * 4096);
        #pragma unroll
        for (int it = 0; it < 4; it++) {
            const int ch_l = it * 32 + (tid >> 3);
            const int p0 = (tid & 7) * 16;
            *(uint4*)&vtb[(long)(nc + ch_l) * 4096 + pixb + p0] =
                *(const uint4*)&s8[ch_l * 144 + p0];
        }
    }
}

// ---------------------------------------------------------------------------
// Fused flash attention (fp8 MX MFMA, unit scales):
//   ao[pix][ch] = (sum_j exp2(qscale * q.k_j) * v_j) / (sum_j exp2(...))
// Block: 64 Q-rows, full 4096-KV sweep in 32 tiles of 128. 512 threads,
// 8 waves. S-phase wave tile: 16 rows x 64 cols (Q frags in registers,
// K frags global->reg, ping-pong prefetch over 4 D-steps). P (fp8) passes
// through an XOR-swizzled 64x128 LDS tile. PV-phase wave tile: 64 rows x
// 64 ch (V frags global->reg). l accumulated in registers across tiles.
// ---------------------------------------------------------------------------
__global__ __launch_bounds__(512, 2) void flash_attn(const uint8_t* __restrict__ q8,
                                                     const uint8_t* __restrict__ k8,
                                                     const uint8_t* __restrict__ vt8,
                                                     uint16_t* __restrict__ ao) {
    __shared__ __align__(16) uint8_t Pl[64 * 128];      // fp8 P tile (swizzled)
    __shared__ float lpart[8][16];
    __shared__ float linv[64];
    __shared__ __align__(16) uint16_t obuf[64 * 256];   // epilogue repack

    const int tid = threadIdx.x;
    const int lane = tid & 63;
    const int wave = tid >> 6;
    const int fr = lane & 15;
    const int quad = lane >> 4;

    // XCD-chunked swizzle: 32 consecutive logical blocks per XCD (1 batch
    // worth of K/V = 4 MB per 2 XCDs -> L2-resident sliding window).
    const int lb = ((blockIdx.x & 7) << 5) | (blockIdx.x >> 3);
    const int batch = lb >> 6;
    const int mt = lb & 63;
    const long qbase = (long)batch * 4096 + mt * 64;   // row base in q8/ao

    const int wm = (wave >> 1) * 16;    // S-phase row slice (16 rows)
    const int wc = (wave & 1) * 64;     // S-phase col slice (64 cols)
    const float qscale = 0.06375871540654937f;   // log2(e)/sqrt(512)

    // Q fragments: A-rows wm+fr, bytes kt*128 + quad*32 .. +31 (stays in reg)
    v8i aQ[4];
    {
        const uint8_t* qp = q8 + (qbase + wm + fr) * 512 + quad * 32;
        #pragma unroll
        for (int kt = 0; kt < 4; kt++) {
            const uint4 lo = *(const uint4*)(qp + kt * 128);
            const uint4 hi = *(const uint4*)(qp + kt * 128 + 16);
            aQ[kt] = (v8i){(int)lo.x, (int)lo.y, (int)lo.z, (int)lo.w,
                           (int)hi.x, (int)hi.y, (int)hi.z, (int)hi.w};
        }
    }
    const uint8_t* krow = k8 + (long)batch * (4096L * 512) +
                          (long)(wc + fr) * 512 + quad * 32;
    const uint8_t* vrow = vt8 + (long)batch * (512L * 4096) +
                          (long)(wave * 64 + fr) * 4096 + quad * 32;

    floatx4 oacc[4][4];                 // [mi][ni]: rows mi*16.., ch wave*64+ni*16..
    #pragma unroll
    for (int i = 0; i < 4; i++)
        #pragma unroll
        for (int j = 0; j < 4; j++) oacc[i][j] = (floatx4){0.f, 0.f, 0.f, 0.f};
    float lsum[4] = {0.f, 0.f, 0.f, 0.f};

#define LOADK(dst, kt_)                                                        \
    do {                                                                       \
        _Pragma("unroll")                                                      \
        for (int ni = 0; ni < 4; ni++) {                                       \
            const uint8_t* kp = ktb + (long)ni * (16L * 512) + (kt_) * 128;    \
            const uint4 lo = *(const uint4*)kp;                                \
            const uint4 hi = *(const uint4*)(kp + 16);                         \
            dst[ni] = (v8i){(int)lo.x, (int)lo.y, (int)lo.z, (int)lo.w,        \
                            (int)hi.x, (int)hi.y, (int)hi.z, (int)hi.w};       \
        }                                                                      \
    } while (0)

#define SSTEP(kt_, bK)                                                         \
    do {                                                                       \
        _Pragma("unroll")                                                      \
        for (int ni = 0; ni < 4; ni++)                                         \
            sacc[ni] = __builtin_amdgcn_mfma_scale_f32_16x16x128_f8f6f4(       \
                aQ[kt_], bK[ni], sacc[ni], 0, 0, 0, 0x7f7f7f7fu, 0,            \
                0x7f7f7f7fu);                                                  \
    } while (0)

    for (int t = 0; t < 32; t++) {
        const uint8_t* ktb = krow + (long)t * (128L * 512);
        // ---- S = Q @ K_tile^T (16x64 per wave), K ping-pong prefetch ----
        floatx4 sacc[4];
        #pragma unroll
        for (int ni = 0; ni < 4; ni++) sacc[ni] = (floatx4){0.f, 0.f, 0.f, 0.f};
        {
            v8i bKa[4], bKb[4];
            LOADK(bKa, 0);
            LOADK(bKb, 1);
            SSTEP(0, bKa);
            LOADK(bKa, 2);
            SSTEP(1, bKb);
            LOADK(bKb, 3);
            SSTEP(2, bKa);
            SSTEP(3, bKb);
        }
        // ---- V fragments for this tile (latency hides under exp2/pack) ----
        v8i bV[4];
        #pragma unroll
        for (int ni = 0; ni < 4; ni++) {
            const uint8_t* vp = vrow + (long)ni * (16L * 4096) + t * 128;
            const uint4 lo = *(const uint4*)vp;
            const uint4 hi = *(const uint4*)(vp + 16);
            bV[ni] = (v8i){(int)lo.x, (int)lo.y, (int)lo.z, (int)lo.w,
                           (int)hi.x, (int)hi.y, (int)hi.z, (int)hi.w};
        }
        // ---- p = exp2(s*scale); accumulate l; pack fp8 ----
        unsigned pk[4];
        #pragma unroll
        for (int ni = 0; ni < 4; ni++) {
            const float p0 = exp2f(sacc[ni][0] * qscale);
            const float p1 = exp2f(sacc[ni][1] * qscale);
            const float p2 = exp2f(sacc[ni][2] * qscale);
            const float p3 = exp2f(sacc[ni][3] * qscale);
            lsum[0] += p0;
            lsum[1] += p1;
            lsum[2] += p2;
            lsum[3] += p3;
            pk[ni] = pk_fp8x4(p0, p1, p2, p3);
        }
        __syncthreads();   // all waves done reading P(t-1)
        // ---- scatter P bytes into swizzled LDS tile ----
        #pragma unroll
        for (int ni = 0; ni < 4; ni++) {
            const int chunk = ((wave & 1) << 2) | ni;   // 16B chunk = col>>4
            #pragma unroll
            for (int r = 0; r < 4; r++) {
                const int prow = wm + quad * 4 + r;
                Pl[prow * 128 + ((chunk ^ (prow & 7)) << 4) + fr] =
                    (uint8_t)(pk[ni] >> (8 * r));
            }
        }
        __syncthreads();   // P(t) visible
        // ---- O += P @ V_tile (64 rows x 64 ch per wave, K=128 in one mfma) --
        #pragma unroll
        for (int mi = 0; mi < 4; mi++) {
            const int prow = mi * 16 + fr;
            const int sw8 = fr & 7;
            const uint4 lo = *(const uint4*)&Pl[prow * 128 + (((2 * quad) ^ sw8) << 4)];
            const uint4 hi = *(const uint4*)&Pl[prow * 128 + (((2 * quad + 1) ^ sw8) << 4)];
            const v8i aP = (v8i){(int)lo.x, (int)lo.y, (int)lo.z, (int)lo.w,
                                 (int)hi.x, (int)hi.y, (int)hi.z, (int)hi.w};
            #pragma unroll
            for (int ni = 0; ni < 4; ni++)
                oacc[mi][ni] = __builtin_amdgcn_mfma_scale_f32_16x16x128_f8f6f4(
                    aP, bV[ni], oacc[mi][ni], 0, 0, 0, 0x7f7f7f7fu, 0,
                    0x7f7f7f7fu);
        }
    }
#undef LOADK
#undef SSTEP

    // ---- l reduction: over fr (16 lanes), then over wave pairs ----
    #pragma unroll
    for (int r = 0; r < 4; r++) {
        #pragma unroll
        for (int off = 1; off < 16; off <<= 1)
            lsum[r] += __shfl_xor(lsum[r], off);
    }
    if ((lane & 15) == 0) {
        #pragma unroll
        for (int r = 0; r < 4; r++) lpart[wave][quad * 4 + r] = lsum[r];
    }
    __syncthreads();
    if (tid < 64) {
        const int j = tid >> 4;
        const float L = lpart[2 * j][tid & 15] + lpart[2 * j + 1][tid & 15];
        linv[tid] = __builtin_amdgcn_rcpf(L);
    }
    __syncthreads();
    // ---- normalize + store (two 256-ch halves through obuf) ----
    #pragma unroll
    for (int hh = 0; hh < 2; hh++) {
        if ((wave >> 2) == hh) {
            #pragma unroll
            for (int mi = 0; mi < 4; mi++)
                #pragma unroll
                for (int ni = 0; ni < 4; ni++)
                    #pragma unroll
                    for (int r = 0; r < 4; r++) {
                        const int row = mi * 16 + quad * 4 + r;
                        const int col = (wave & 3) * 64 + ni * 16 + fr;
                        obuf[row * 256 + col] = f2b(oacc[mi][ni][r] * linv[row]);
                    }
        }
        __syncthreads();
        {
            const int srow = tid >> 3;
            const int sc = tid & 7;
            uint16_t* dst = ao + (qbase + srow) * 512 + hh * 256;
            const uint16_t* src = &obuf[srow * 256];
            #pragma unroll
            for (int it = 0; it < 4; it++)
                *(uint4*)(dst + (sc + it * 8) * 8) =
                    *(const uint4*)(src + (sc + it * 8) * 8);
        }
        __syncthreads();
    }
}

// ---------------------------------------------------------------------------
// Projection GEMM (bf16 MFMA): out = ao @ wp^T + bp + x   (f32 out)
// ---------------------------------------------------------------------------
__global__ __launch_bounds__(256) void gemm_proj(const uint16_t* __restrict__ A,
                                                 const uint16_t* __restrict__ B,
                                                 float* __restrict__ Cout,
                                                 const float* __restrict__ bias,
                                                 const float* __restrict__ resid) {
    __shared__ __align__(16) uint16_t smem[128 * 136];
    uint16_t* sA = smem;
    uint16_t* sB = smem + 8192;
    const int N = 512;

    const int tid = threadIdx.x;
    const long m0 = (long)blockIdx.y * 128;
    const long n0 = (long)blockIdx.x * 128;

    const int lane = tid & 63;
    const int wave = tid >> 6;
    const int wm = (wave & 1) * 64;
    const int wn = (wave >> 1) * 64;
    const int fr = lane & 15;
    const int fh = lane >> 4;
    const int sw = fr & 7;

    floatx4 acc[4][4];
    #pragma unroll
    for (int i = 0; i < 4; i++)
        #pragma unroll
        for (int j = 0; j < 4; j++) acc[i][j] = (floatx4){0.f, 0.f, 0.f, 0.f};

    for (int kt = 0; kt < 512; kt += 64) {
        __syncthreads();
        #pragma unroll
        for (int i = 0; i < 4; i++) {
            const int c = i * 256 + tid;
            const int row = c >> 3;
            const int gj = (c & 7) ^ (row & 7);
            lds_copy16(&sA[c * 8], A + (m0 + row) * 512L + kt + gj * 8);
            lds_copy16(&sB[c * 8], B + (n0 + row) * 512L + kt + gj * 8);
        }
        __syncthreads();
        #pragma unroll
        for (int kk = 0; kk < 64; kk += 32) {
            const int jx = ((fh + (kk >> 3)) ^ sw) * 8;
            bf16x8 av[4], bv[4];
            #pragma unroll
            for (int mi = 0; mi < 4; mi++)
                av[mi] = *(const bf16x8*)&sA[(wm + mi * 16 + fr) * 64 + jx];
            #pragma unroll
            for (int ni = 0; ni < 4; ni++)
                bv[ni] = *(const bf16x8*)&sB[(wn + ni * 16 + fr) * 64 + jx];
            #pragma unroll
            for (int mi = 0; mi < 4; mi++)
                #pragma unroll
                for (int ni = 0; ni < 4; ni++)
                    acc[mi][ni] = __builtin_amdgcn_mfma_f32_16x16x32_bf16(
                        av[mi], bv[ni], acc[mi][ni], 0, 0, 0);
        }
    }

    const int quad = lane >> 4;
    #pragma unroll
    for (int ni = 0; ni < 4; ni++) {
        const long col = n0 + wn + ni * 16 + fr;
        const float bv_ = bias[col];
        #pragma unroll
        for (int mi = 0; mi < 4; mi++) {
            #pragma unroll
            for (int r = 0; r < 4; r++) {
                const long row = m0 + wm + mi * 16 + quad * 4 + r;
                Cout[row * N + col] = acc[mi][ni][r] + bv_ + resid[row * N + col];
            }
        }
    }
}

// ---------------------------------------------------------------------------
extern "C" void kernel_launch(void* const* d_in, const int* in_sizes, int n_in,
                              void* d_out, int out_size, void* d_ws, size_t ws_size,
                              hipStream_t stream) {
    const float* x  = (const float*)d_in[0];
    const float* gg = (const float*)d_in[1];
    const float* gb = (const float*)d_in[2];
    const float* wq = (const float*)d_in[3];
    const float* bq = (const float*)d_in[4];
    const float* wk = (const float*)d_in[5];
    const float* bk = (const float*)d_in[6];
    const float* wv = (const float*)d_in[7];
    const float* bv = (const float*)d_in[8];
    const float* wp = (const float*)d_in[9];
    const float* bp = (const float*)d_in[10];
    float* out = (float*)d_out;

    char* ws = (char*)d_ws;
    size_t off = 0;
    auto alloc = [&](size_t bytes) {
        char* p = ws + off;
        off += (bytes + 255) & ~(size_t)255;
        return p;
    };
    float*    stats = (float*)alloc(128 * 2 * sizeof(float));
    uint16_t* h     = (uint16_t*)alloc(16384L * 512 * 2);
    uint16_t* wT    = (uint16_t*)alloc(4L * 512 * 512 * 2);
    uint8_t*  q8    = (uint8_t*)alloc(16384L * 512);
    uint8_t*  k8    = (uint8_t*)alloc(16384L * 512);
    uint8_t*  vt8   = (uint8_t*)alloc(16384L * 512);
    uint16_t* ao    = (uint16_t*)alloc(16384L * 512 * 2);
    if (off > ws_size) return;  // workspace too small -> fail visibly

    gn_stats<<<128, 256, 0, stream>>>(x, stats);
    gn_apply<<<8192, 256, 0, stream>>>(x, stats, gg, gb, h);
    wcast_transpose<<<dim3(8, 8, 4), 256, 0, stream>>>(wq, wk, wv, wp, wT);

    // q / k / v^T (fp8) in one dispatch
    qkv_gemm<<<dim3(12, 128), 256, 0, stream>>>(h, wT, bq, bk, bv, q8, k8, vt8);
    // fused softmax(QK^T)V -> ao (bf16)
    flash_attn<<<dim3(256), dim3(512), 0, stream>>>(q8, k8, vt8, ao);
    // out = x + ao @ wp + bp
    gemm_proj<<<dim3(4, 128), 256, 0, stream>>>(ao, wT + 3 * 262144, out, bp, x);
}

// Round 2
// 318.067 us; speedup vs baseline: 1.5612x; 1.5612x over previous
//
#include <hip/hip_runtime.h>
#include <cstdint>

// ---------------------------------------------------------------------------
// VAE attention block: GN -> QKV 1x1 conv -> softmax(QK^T) V -> proj + x
// B=4, H=W=64 (N=4096 pixels/batch), C=512, GROUPS=32
// R8: flash_attn v2 — K tile staged through LDS via global_load_lds
//   (v1 loaded K per-lane from global: 4x redundant reads, ~8 MB L2/tile/XCD,
//    latency-bound at 318 us with MfmaUtil 8.7%).
//   - sK: 64 KB K tile [4 kt][128 rows][128 B], gemm_f8-style pre-swizzled
//     source so the XOR read pattern inverts to identity k-order (matches
//     unswizzled Q regs)
//   - 3 barriers/tile: free-sK / stage+drain / P-visible
//   - V stays per-lane global->reg (no intra-block redundancy; compiler
//     counted-vmcnt hides latency under S-phase MFMAs)
// ---------------------------------------------------------------------------

typedef __bf16 bf16_t;
typedef bf16_t bf16x8 __attribute__((ext_vector_type(8)));
typedef float floatx4 __attribute__((ext_vector_type(4)));
typedef int v8i __attribute__((ext_vector_type(8)));

__device__ __forceinline__ uint16_t f2b(float f) {
    uint32_t u = __builtin_bit_cast(uint32_t, f);
    u += 0x7fffu + ((u >> 16) & 1u);
    return (uint16_t)(u >> 16);
}
__device__ __forceinline__ float b2f(uint16_t h) {
    uint32_t u = ((uint32_t)h) << 16;
    return __builtin_bit_cast(float, u);
}
// pack 4 floats -> 4 fp8 e4m3 bytes (byte 0 = first arg)
__device__ __forceinline__ unsigned pk_fp8x4(float a, float b, float c, float d) {
    int w = __builtin_amdgcn_cvt_pk_fp8_f32(a, b, 0, false);
    w = __builtin_amdgcn_cvt_pk_fp8_f32(c, d, w, true);
    return (unsigned)w;
}

__device__ __forceinline__ void lds_copy16(void* lds, const void* glob) {
    __builtin_amdgcn_global_load_lds(
        (__attribute__((address_space(1))) void*)(void*)glob,
        (__attribute__((address_space(3))) void*)lds,
        16, 0, 0);
}

// ---------------------------------------------------------------------------
// GroupNorm stats: one block per (batch, group).
// ---------------------------------------------------------------------------
__global__ __launch_bounds__(256) void gn_stats(const float* __restrict__ x,
                                                float* __restrict__ stats) {
    const int bg = blockIdx.x;            // 0..127
    const int tid = threadIdx.x;
    const int b = bg >> 5, g = bg & 31;
    const float* base = x + (long)b * (4096L * 512) + g * 16;
    float s = 0.f, sq = 0.f;
    #pragma unroll 8
    for (int i = 0; i < 64; i++) {
        int idx4 = tid + i * 256;          // float4 index within group
        int pixel = idx4 >> 2, c4 = idx4 & 3;
        const float4 v = *(const float4*)(base + (long)pixel * 512 + c4 * 4);
        s += v.x + v.y + v.z + v.w;
        sq += v.x * v.x + v.y * v.y + v.z * v.z + v.w * v.w;
    }
    #pragma unroll
    for (int off = 32; off > 0; off >>= 1) {
        s += __shfl_down(s, off);
        sq += __shfl_down(sq, off);
    }
    __shared__ float rs[4], rq[4];
    const int lane = tid & 63, w = tid >> 6;
    if (lane == 0) { rs[w] = s; rq[w] = sq; }
    __syncthreads();
    if (tid == 0) {
        float S = rs[0] + rs[1] + rs[2] + rs[3];
        float Q = rq[0] + rq[1] + rq[2] + rq[3];
        float mean = S * (1.f / 65536.f);
        float var = Q * (1.f / 65536.f) - mean * mean;
        stats[bg * 2 + 0] = mean;
        stats[bg * 2 + 1] = rsqrtf(var + 1e-5f);
    }
}

// ---------------------------------------------------------------------------
// GroupNorm apply: h_bf16 = (x-mean)*rstd*gamma + beta.  4 elems/thread.
// ---------------------------------------------------------------------------
__global__ __launch_bounds__(256) void gn_apply(const float* __restrict__ x,
                                                const float* __restrict__ stats,
                                                const float* __restrict__ gamma,
                                                const float* __restrict__ beta,
                                                uint16_t* __restrict__ h) {
    const long idx4 = (long)blockIdx.x * 256 + threadIdx.x;   // 0..2097151
    const long e0 = idx4 * 4;
    const int c = (int)(e0 & 511);
    const int b = (int)(e0 >> 21);                            // 4096*512 = 2^21
    const float2 st = ((const float2*)stats)[b * 32 + (c >> 4)];
    const float4 v = ((const float4*)x)[idx4];
    const float4 gm = ((const float4*)gamma)[c >> 2];
    const float4 bt = ((const float4*)beta)[c >> 2];
    union { ushort4 u; uint16_t s[4]; } o;
    o.s[0] = f2b((v.x - st.x) * st.y * gm.x + bt.x);
    o.s[1] = f2b((v.y - st.x) * st.y * gm.y + bt.y);
    o.s[2] = f2b((v.z - st.x) * st.y * gm.z + bt.z);
    o.s[3] = f2b((v.w - st.x) * st.y * gm.w + bt.w);
    ((ushort4*)h)[idx4] = o.u;
}

// ---------------------------------------------------------------------------
// Cast+transpose weights: wT[d][c] = bf16(w[c][d]), 512x512, 64x64 LDS tiles.
// ---------------------------------------------------------------------------
__global__ __launch_bounds__(256) void wcast_transpose(const float* __restrict__ w0,
                                                       const float* __restrict__ w1,
                                                       const float* __restrict__ w2,
                                                       const float* __restrict__ w3,
                                                       uint16_t* __restrict__ out) {
    const float* ws[4] = {w0, w1, w2, w3};
    const float* w = ws[blockIdx.z];
    uint16_t* o = out + (long)blockIdx.z * 512 * 512;
    __shared__ uint16_t t[64][65];
    const int nb = blockIdx.x * 64, kb = blockIdx.y * 64;
    const int lc = threadIdx.x & 63, lg = threadIdx.x >> 6;
    #pragma unroll
    for (int i = 0; i < 16; i++) {
        int r = lg * 16 + i;
        t[lc][r] = f2b(w[(long)(kb + r) * 512 + nb + lc]);   // t[n_loc][k_loc]
    }
    __syncthreads();
    #pragma unroll
    for (int i = 0; i < 16; i++) {
        int r = lg * 16 + i;
        o[(long)(nb + r) * 512 + kb + lc] = t[r][lc];        // wT[n][k]
    }
}

// ---------------------------------------------------------------------------
// Fused QKV GEMM (bf16 MFMA): [16384,512] x [1536,512]^T.  Grid (12, 128).
// Outputs fp8 e4m3: cols 0-511 -> q, 512-1023 -> k, 1024-1535 -> v stored
// TRANSPOSED (vt[b][ch][pix]).  No scale on q (moved to flash epilogue).
// ---------------------------------------------------------------------------
__global__ __launch_bounds__(256) void qkv_gemm(const uint16_t* __restrict__ h,
                                                const uint16_t* __restrict__ wT,
                                                const float* __restrict__ bq,
                                                const float* __restrict__ bk,
                                                const float* __restrict__ bv,
                                                uint8_t* __restrict__ q,
                                                uint8_t* __restrict__ k,
                                                uint8_t* __restrict__ vt) {
    __shared__ __align__(16) uint16_t smem[128 * 136];
    uint16_t* sA = smem;
    uint16_t* sB = smem + 8192;

    const int tid = threadIdx.x;
    const long m0 = (long)blockIdx.y * 128;
    const int n0 = blockIdx.x * 128;

    const int lane = tid & 63;
    const int wave = tid >> 6;
    const int wm = (wave & 1) * 64;
    const int wn = (wave >> 1) * 64;
    const int fr = lane & 15;
    const int fh = lane >> 4;
    const int sw = fr & 7;

    floatx4 acc[4][4];
    #pragma unroll
    for (int i = 0; i < 4; i++)
        #pragma unroll
        for (int j = 0; j < 4; j++) acc[i][j] = (floatx4){0.f, 0.f, 0.f, 0.f};

    for (int kt = 0; kt < 512; kt += 64) {
        __syncthreads();
        #pragma unroll
        for (int i = 0; i < 4; i++) {
            const int c = i * 256 + tid;
            const int row = c >> 3;
            const int gj = (c & 7) ^ (row & 7);
            lds_copy16(&sA[c * 8], h + (m0 + row) * 512L + kt + gj * 8);
            lds_copy16(&sB[c * 8], wT + (n0 + row) * 512L + kt + gj * 8);
        }
        __syncthreads();
        #pragma unroll
        for (int kk = 0; kk < 64; kk += 32) {
            const int jx = ((fh + (kk >> 3)) ^ sw) * 8;
            bf16x8 av[4], bv_[4];
            #pragma unroll
            for (int mi = 0; mi < 4; mi++)
                av[mi] = *(const bf16x8*)&sA[(wm + mi * 16 + fr) * 64 + jx];
            #pragma unroll
            for (int ni = 0; ni < 4; ni++)
                bv_[ni] = *(const bf16x8*)&sB[(wn + ni * 16 + fr) * 64 + jx];
            #pragma unroll
            for (int mi = 0; mi < 4; mi++)
                #pragma unroll
                for (int ni = 0; ni < 4; ni++)
                    acc[mi][ni] = __builtin_amdgcn_mfma_f32_16x16x32_bf16(
                        av[mi], bv_[ni], acc[mi][ni], 0, 0, 0);
        }
    }

    const int quad = lane >> 4;
    const int w = n0 >> 9;          // 0=q, 1=k, 2=v(T)
    const int nc = n0 & 511;
    const float* bias = (w == 0) ? bq : (w == 1) ? bk : bv;
    __syncthreads();
    if (w < 2) {
        // repack bf16 rows, then fp8-convert during the coalesced store
        #pragma unroll
        for (int ni = 0; ni < 4; ni++) {
            const int col_l = wn + ni * 16 + fr;
            const float bb = bias[nc + col_l];
            #pragma unroll
            for (int mi = 0; mi < 4; mi++) {
                #pragma unroll
                for (int r = 0; r < 4; r++) {
                    const int row_l = wm + mi * 16 + quad * 4 + r;
                    smem[row_l * 136 + col_l] = f2b(acc[mi][ni][r] + bb);
                }
            }
        }
        __syncthreads();
        uint8_t* out = (w == 0) ? q : k;
        #pragma unroll
        for (int it = 0; it < 8; it++) {
            const int row_l = it * 16 + (tid >> 4);
            const int c0 = (tid & 15) * 8;
            const uint4 d = *(const uint4*)&smem[row_l * 136 + c0];
            const uint16_t* e = (const uint16_t*)&d;
            uint2 o;
            o.x = pk_fp8x4(b2f(e[0]), b2f(e[1]), b2f(e[2]), b2f(e[3]));
            o.y = pk_fp8x4(b2f(e[4]), b2f(e[5]), b2f(e[6]), b2f(e[7]));
            *(uint2*)&out[(m0 + row_l) * 512 + nc + c0] = o;
        }
    } else {
        // transposed fp8 repack: s8[ch][pix], byte stride 144 (16B-aligned)
        uint8_t* s8 = (uint8_t*)smem;
        #pragma unroll
        for (int ni = 0; ni < 4; ni++) {
            const int ch_l = wn + ni * 16 + fr;
            const float bb = bias[nc + ch_l];
            #pragma unroll
            for (int mi = 0; mi < 4; mi++) {
                const int pix0 = wm + mi * 16 + quad * 4;
                *(unsigned*)&s8[ch_l * 144 + pix0] =
                    pk_fp8x4(acc[mi][ni][0] + bb, acc[mi][ni][1] + bb,
                             acc[mi][ni][2] + bb, acc[mi][ni][3] + bb);
            }
        }
        __syncthreads();
        const long b = m0 >> 12;
        const int pixb = (int)(m0 & 4095);
        uint8_t* vtb = vt + b * (512L * 4096);
        #pragma unroll
        for (int it = 0; it < 4; it++) {
            const int ch_l = it * 32 + (tid >> 3);
            const int p0 = (tid & 7) * 16;
            *(uint4*)&vtb[(long)(nc + ch_l) * 4096 + pixb + p0] =
                *(const uint4*)&s8[ch_l * 144 + p0];
        }
    }
}

// ---------------------------------------------------------------------------
// Fused flash attention v2 (fp8 MX MFMA, unit scales):
//   ao[pix][ch] = (sum_j exp2(qscale * q.k_j) * v_j) / (sum_j exp2(...))
// Block: 64 Q-rows, full 4096-KV sweep in 32 tiles of 128. 512 threads,
// 8 waves. K tile staged in LDS (64 KB, global_load_lds, pre-swizzled
// source so swizzled reads return identity k-order). Q in registers.
// V per-lane global->reg. P (fp8) via 8 KB XOR-swizzled LDS tile.
// Row-sums l in registers across tiles, reduced once at the end.
// ---------------------------------------------------------------------------
__global__ __launch_bounds__(512, 2) void flash_attn(const uint8_t* __restrict__ q8,
                                                     const uint8_t* __restrict__ k8,
                                                     const uint8_t* __restrict__ vt8,
                                                     uint16_t* __restrict__ ao) {
    __shared__ __align__(16) uint8_t sK[65536];         // [4 kt][128 row][128 B]
    __shared__ __align__(16) uint8_t Pl[64 * 128];      // fp8 P tile (swizzled)
    __shared__ float lpart[8][16];
    __shared__ float linv[64];
    __shared__ __align__(16) uint16_t obuf[64 * 256];   // epilogue repack

    const int tid = threadIdx.x;
    const int lane = tid & 63;
    const int wave = tid >> 6;
    const int fr = lane & 15;
    const int quad = lane >> 4;
    const int sw = fr & 7;

    // XCD-chunked swizzle: 32 consecutive logical blocks per XCD (1 batch
    // worth of K/V per 2 XCDs -> L2-resident).
    const int lb = ((blockIdx.x & 7) << 5) | (blockIdx.x >> 3);
    const int batch = lb >> 6;
    const int mt = lb & 63;
    const long qbase = (long)batch * 4096 + mt * 64;   // row base in q8/ao

    const int wm = (wave >> 1) * 16;    // S-phase row slice (16 rows)
    const int wc = (wave & 1) * 64;     // S-phase col slice (64 cols)
    const float qscale = 0.06375871540654937f;   // log2(e)/sqrt(512)

    // Q fragments: A-rows wm+fr, bytes kt*128 + quad*32 .. +31 (stays in reg)
    v8i aQ[4];
    {
        const uint8_t* qp = q8 + (qbase + wm + fr) * 512 + quad * 32;
        #pragma unroll
        for (int kt = 0; kt < 4; kt++) {
            const uint4 lo = *(const uint4*)(qp + kt * 128);
            const uint4 hi = *(const uint4*)(qp + kt * 128 + 16);
            aQ[kt] = (v8i){(int)lo.x, (int)lo.y, (int)lo.z, (int)lo.w,
                           (int)hi.x, (int)hi.y, (int)hi.z, (int)hi.w};
        }
    }
    const uint8_t* kbb = k8 + (long)batch * (4096L * 512);
    const uint8_t* vrow = vt8 + (long)batch * (512L * 4096) +
                          (long)(wave * 64 + fr) * 4096 + quad * 32;

    floatx4 oacc[4][4];                 // [mi][ni]: rows mi*16.., ch wave*64+ni*16..
    #pragma unroll
    for (int i = 0; i < 4; i++)
        #pragma unroll
        for (int j = 0; j < 4; j++) oacc[i][j] = (floatx4){0.f, 0.f, 0.f, 0.f};
    float lsum[4] = {0.f, 0.f, 0.f, 0.f};

    for (int t = 0; t < 32; t++) {
        __syncthreads();   // B1: PV(t-1) done with Pl; S(t-1) done with sK
        // ---- stage K tile t -> sK (8 x 16B per thread, swizzled source) ----
        {
            const uint8_t* kb = kbb + (long)t * (128L * 512);
            #pragma unroll
            for (int i = 0; i < 8; i++) {
                const int chunk = i * 512 + tid;      // 0..4095
                const int kt = chunk >> 10;
                const int c = chunk & 1023;
                const int row = c >> 3;
                const int gj = (c & 7) ^ (row & 7);
                lds_copy16(&sK[kt * 16384 + c * 16],
                           kb + row * 512 + kt * 128 + gj * 16);
            }
        }
        __syncthreads();   // B2: vmcnt drain -> sK ready
        // ---- V fragments (reg-destined; latency hides under S phase) ----
        v8i bV[4];
        #pragma unroll
        for (int ni = 0; ni < 4; ni++) {
            const uint8_t* vp = vrow + (long)ni * (16L * 4096) + t * 128;
            const uint4 lo = *(const uint4*)vp;
            const uint4 hi = *(const uint4*)(vp + 16);
            bV[ni] = (v8i){(int)lo.x, (int)lo.y, (int)lo.z, (int)lo.w,
                           (int)hi.x, (int)hi.y, (int)hi.z, (int)hi.w};
        }
        // ---- S = Q @ K_tile^T (16x64 per wave) from LDS ----
        floatx4 sacc[4];
        #pragma unroll
        for (int ni = 0; ni < 4; ni++) sacc[ni] = (floatx4){0.f, 0.f, 0.f, 0.f};
        #pragma unroll
        for (int kt = 0; kt < 4; kt++) {
            v8i bK[4];
            #pragma unroll
            for (int ni = 0; ni < 4; ni++) {
                const int row = wc + ni * 16 + fr;
                const uint8_t* base = &sK[kt * 16384 + row * 128];
                const uint4 lo = *(const uint4*)(base + (((2 * quad) ^ sw) << 4));
                const uint4 hi = *(const uint4*)(base + (((2 * quad + 1) ^ sw) << 4));
                bK[ni] = (v8i){(int)lo.x, (int)lo.y, (int)lo.z, (int)lo.w,
                               (int)hi.x, (int)hi.y, (int)hi.z, (int)hi.w};
            }
            #pragma unroll
            for (int ni = 0; ni < 4; ni++)
                sacc[ni] = __builtin_amdgcn_mfma_scale_f32_16x16x128_f8f6f4(
                    aQ[kt], bK[ni], sacc[ni], 0, 0, 0, 0x7f7f7f7fu, 0,
                    0x7f7f7f7fu);
        }
        // ---- p = exp2(s*scale); accumulate l; pack fp8 ----
        unsigned pk[4];
        #pragma unroll
        for (int ni = 0; ni < 4; ni++) {
            const float p0 = exp2f(sacc[ni][0] * qscale);
            const float p1 = exp2f(sacc[ni][1] * qscale);
            const float p2 = exp2f(sacc[ni][2] * qscale);
            const float p3 = exp2f(sacc[ni][3] * qscale);
            lsum[0] += p0;
            lsum[1] += p1;
            lsum[2] += p2;
            lsum[3] += p3;
            pk[ni] = pk_fp8x4(p0, p1, p2, p3);
        }
        // ---- scatter P bytes into swizzled LDS tile ----
        #pragma unroll
        for (int ni = 0; ni < 4; ni++) {
            const int chunk = ((wave & 1) << 2) | ni;   // 16B chunk = col>>4
            #pragma unroll
            for (int r = 0; r < 4; r++) {
                const int prow = wm + quad * 4 + r;
                Pl[prow * 128 + ((chunk ^ (prow & 7)) << 4) + fr] =
                    (uint8_t)(pk[ni] >> (8 * r));
            }
        }
        __syncthreads();   // B3: P(t) visible
        // ---- O += P @ V_tile (64 rows x 64 ch per wave, K=128) ----
        #pragma unroll
        for (int mi = 0; mi < 4; mi++) {
            const int prow = mi * 16 + fr;
            const uint4 lo = *(const uint4*)&Pl[prow * 128 + (((2 * quad) ^ sw) << 4)];
            const uint4 hi = *(const uint4*)&Pl[prow * 128 + (((2 * quad + 1) ^ sw) << 4)];
            const v8i aP = (v8i){(int)lo.x, (int)lo.y, (int)lo.z, (int)lo.w,
                                 (int)hi.x, (int)hi.y, (int)hi.z, (int)hi.w};
            #pragma unroll
            for (int ni = 0; ni < 4; ni++)
                oacc[mi][ni] = __builtin_amdgcn_mfma_scale_f32_16x16x128_f8f6f4(
                    aP, bV[ni], oacc[mi][ni], 0, 0, 0, 0x7f7f7f7fu, 0,
                    0x7f7f7f7fu);
        }
    }

    // ---- l reduction: over fr (16 lanes), then over wave pairs ----
    #pragma unroll
    for (int r = 0; r < 4; r++) {
        #pragma unroll
        for (int off = 1; off < 16; off <<= 1)
            lsum[r] += __shfl_xor(lsum[r], off);
    }
    if ((lane & 15) == 0) {
        #pragma unroll
        for (int r = 0; r < 4; r++) lpart[wave][quad * 4 + r] = lsum[r];
    }
    __syncthreads();
    if (tid < 64) {
        const int j = tid >> 4;
        const float L = lpart[2 * j][tid & 15] + lpart[2 * j + 1][tid & 15];
        linv[tid] = __builtin_amdgcn_rcpf(L);
    }
    __syncthreads();
    // ---- normalize + store (two 256-ch halves through obuf) ----
    #pragma unroll
    for (int hh = 0; hh < 2; hh++) {
        if ((wave >> 2) == hh) {
            #pragma unroll
            for (int mi = 0; mi < 4; mi++)
                #pragma unroll
                for (int ni = 0; ni < 4; ni++)
                    #pragma unroll
                    for (int r = 0; r < 4; r++) {
                        const int row = mi * 16 + quad * 4 + r;
                        const int col = (wave & 3) * 64 + ni * 16 + fr;
                        obuf[row * 256 + col] = f2b(oacc[mi][ni][r] * linv[row]);
                    }
        }
        __syncthreads();
        {
            const int srow = tid >> 3;
            const int sc = tid & 7;
            uint16_t* dst = ao + (qbase + srow) * 512 + hh * 256;
            const uint16_t* src = &obuf[srow * 256];
            #pragma unroll
            for (int it = 0; it < 4; it++)
                *(uint4*)(dst + (sc + it * 8) * 8) =
                    *(const uint4*)(src + (sc + it * 8) * 8);
        }
        __syncthreads();
    }
}

// ---------------------------------------------------------------------------
// Projection GEMM (bf16 MFMA): out = ao @ wp^T + bp + x   (f32 out)
// ---------------------------------------------------------------------------
__global__ __launch_bounds__(256) void gemm_proj(const uint16_t* __restrict__ A,
                                                 const uint16_t* __restrict__ B,
                                                 float* __restrict__ Cout,
                                                 const float* __restrict__ bias,
                                                 const float* __restrict__ resid) {
    __shared__ __align__(16) uint16_t smem[128 * 136];
    uint16_t* sA = smem;
    uint16_t* sB = smem + 8192;
    const int N = 512;

    const int tid = threadIdx.x;
    const long m0 = (long)blockIdx.y * 128;
    const long n0 = (long)blockIdx.x * 128;

    const int lane = tid & 63;
    const int wave = tid >> 6;
    const int wm = (wave & 1) * 64;
    const int wn = (wave >> 1) * 64;
    const int fr = lane & 15;
    const int fh = lane >> 4;
    const int sw = fr & 7;

    floatx4 acc[4][4];
    #pragma unroll
    for (int i = 0; i < 4; i++)
        #pragma unroll
        for (int j = 0; j < 4; j++) acc[i][j] = (floatx4){0.f, 0.f, 0.f, 0.f};

    for (int kt = 0; kt < 512; kt += 64) {
        __syncthreads();
        #pragma unroll
        for (int i = 0; i < 4; i++) {
            const int c = i * 256 + tid;
            const int row = c >> 3;
            const int gj = (c & 7) ^ (row & 7);
            lds_copy16(&sA[c * 8], A + (m0 + row) * 512L + kt + gj * 8);
            lds_copy16(&sB[c * 8], B + (n0 + row) * 512L + kt + gj * 8);
        }
        __syncthreads();
        #pragma unroll
        for (int kk = 0; kk < 64; kk += 32) {
            const int jx = ((fh + (kk >> 3)) ^ sw) * 8;
            bf16x8 av[4], bv[4];
            #pragma unroll
            for (int mi = 0; mi < 4; mi++)
                av[mi] = *(const bf16x8*)&sA[(wm + mi * 16 + fr) * 64 + jx];
            #pragma unroll
            for (int ni = 0; ni < 4; ni++)
                bv[ni] = *(const bf16x8*)&sB[(wn + ni * 16 + fr) * 64 + jx];
            #pragma unroll
            for (int mi = 0; mi < 4; mi++)
                #pragma unroll
                for (int ni = 0; ni < 4; ni++)
                    acc[mi][ni] = __builtin_amdgcn_mfma_f32_16x16x32_bf16(
                        av[mi], bv[ni], acc[mi][ni], 0, 0, 0);
        }
    }

    const int quad = lane >> 4;
    #pragma unroll
    for (int ni = 0; ni < 4; ni++) {
        const long col = n0 + wn + ni * 16 + fr;
        const float bv_ = bias[col];
        #pragma unroll
        for (int mi = 0; mi < 4; mi++) {
            #pragma unroll
            for (int r = 0; r < 4; r++) {
                const long row = m0 + wm + mi * 16 + quad * 4 + r;
                Cout[row * N + col] = acc[mi][ni][r] + bv_ + resid[row * N + col];
            }
        }
    }
}

// ---------------------------------------------------------------------------
extern "C" void kernel_launch(void* const* d_in, const int* in_sizes, int n_in,
                              void* d_out, int out_size, void* d_ws, size_t ws_size,
                              hipStream_t stream) {
    const float* x  = (const float*)d_in[0];
    const float* gg = (const float*)d_in[1];
    const float* gb = (const float*)d_in[2];
    const float* wq = (const float*)d_in[3];
    const float* bq = (const float*)d_in[4];
    const float* wk = (const float*)d_in[5];
    const float* bk = (const float*)d_in[6];
    const float* wv = (const float*)d_in[7];
    const float* bv = (const float*)d_in[8];
    const float* wp = (const float*)d_in[9];
    const float* bp = (const float*)d_in[10];
    float* out = (float*)d_out;

    char* ws = (char*)d_ws;
    size_t off = 0;
    auto alloc = [&](size_t bytes) {
        char* p = ws + off;
        off += (bytes + 255) & ~(size_t)255;
        return p;
    };
    float*    stats = (float*)alloc(128 * 2 * sizeof(float));
    uint16_t* h     = (uint16_t*)alloc(16384L * 512 * 2);
    uint16_t* wT    = (uint16_t*)alloc(4L * 512 * 512 * 2);
    uint8_t*  q8    = (uint8_t*)alloc(16384L * 512);
    uint8_t*  k8    = (uint8_t*)alloc(16384L * 512);
    uint8_t*  vt8   = (uint8_t*)alloc(16384L * 512);
    uint16_t* ao    = (uint16_t*)alloc(16384L * 512 * 2);
    if (off > ws_size) return;  // workspace too small -> fail visibly

    gn_stats<<<128, 256, 0, stream>>>(x, stats);
    gn_apply<<<8192, 256, 0, stream>>>(x, stats, gg, gb, h);
    wcast_transpose<<<dim3(8, 8, 4), 256, 0, stream>>>(wq, wk, wv, wp, wT);

    // q / k / v^T (fp8) in one dispatch
    qkv_gemm<<<dim3(12, 128), 256, 0, stream>>>(h, wT, bq, bk, bv, q8, k8, vt8);
    // fused softmax(QK^T)V -> ao (bf16)
    flash_attn<<<dim3(256), dim3(512), 0, stream>>>(q8, k8, vt8, ao);
    // out = x + ao @ wp + bp
    gemm_proj<<<dim3(4, 128), 256, 0, stream>>>(ao, wT + 3 * 262144, out, bp, x);
}